// Round 5
// baseline (733.338 us; speedup 1.0000x reference)
//
#include <hip/hip_runtime.h>
#include <stdint.h>
#include <stddef.h>

// ---------------------------------------------------------------------------
// Round 5: 3 chained GEMMs (gather fused into GEMM-1 A-staging), 32x32x16
// MFMA, 128x128 tile, BK=64, 4 blocks/CU target.
// vs round 4: (a) MODE-0 epilogue stores acc->global bf16 directly (no LDS
// round-trip, no barriers; X is L2/L3-resident so 2B stores write-combine);
// (b) FINAL reduction reads L via volatile u32 with per-lane start rotation
// (bank = 4*(r2&7) + a + i, injective per wave -> 0 conflicts; R4's 6.29e6
// conflicts were the compiler-merged b128 reads of the 136-stride L);
// (c) Wo slice staged in LDS (broadcast reads).
// ---------------------------------------------------------------------------

typedef __attribute__((ext_vector_type(8))) short short8;
typedef __attribute__((ext_vector_type(16))) float f32x16;
typedef __attribute__((ext_vector_type(4))) float floatv4;
typedef __attribute__((ext_vector_type(8))) unsigned short ushort8;

#define GLOAD_LDS16(g, l)                                                      \
  __builtin_amdgcn_global_load_lds(                                            \
      (const __attribute__((address_space(1))) void*)(g),                      \
      (__attribute__((address_space(3))) void*)(l), 16, 0, 0)

__device__ __forceinline__ unsigned short f2bf(float f) {
  unsigned int u = __float_as_uint(f);
  u += 0x7fffu + ((u >> 16) & 1u);  // RNE
  return (unsigned short)(u >> 16);
}
__device__ __forceinline__ float bf2f(unsigned short s) {
  return __uint_as_float(((unsigned int)s) << 16);
}

#define NNODES 100000
#define MTOT   300000
#define HD     512
#define NH     50000

// --- Wt[layer][n][k] = bf16(W[k][n]) ----------------------------------------
__global__ __launch_bounds__(256) void prep_w(const float* __restrict__ W1,
                                              const float* __restrict__ W2,
                                              const float* __restrict__ W3,
                                              unsigned short* __restrict__ Wt) {
  int t = blockIdx.x * 256 + threadIdx.x;  // < 3*512*512
  int layer = t >> 18;
  int r = t & 262143;
  int n = r >> 9, k = r & 511;
  const float* W = layer == 0 ? W1 : (layer == 1 ? W2 : W3);
  Wt[t] = f2bf(W[k * 512 + n]);
}

// --- hb = bf16(h) [50000 x 128] ---------------------------------------------
__global__ __launch_bounds__(256) void prep_hb(const float* __restrict__ h,
                                               unsigned short* __restrict__ hb) {
  int t = blockIdx.x * 256 + threadIdx.x;  // < NH*16
  int v = t >> 4, c8 = (t & 15) * 8;
  const floatv4* hp = (const floatv4*)(h + (size_t)v * 128 + c8);
  floatv4 f0 = hp[0], f1 = hp[1];
  ushort8 o;
#pragma unroll
  for (int e = 0; e < 4; ++e) {
    o[e] = f2bf(f0[e]);
    o[4 + e] = f2bf(f1[e]);
  }
  *(ushort8*)(hb + (size_t)v * 128 + c8) = o;
}

__global__ __launch_bounds__(256) void init_out(float* __restrict__ out,
                                                const float* __restrict__ bo) {
  int t = blockIdx.x * 256 + threadIdx.x;
  if (t < 2 * NNODES) out[t] = bo[t & 1];
}

// --- GEMM: 128x128 tile, BK=64, K=512, 32x32x16 MFMA. ------------------------
template <int GATHER, int FINAL>
__global__ __launch_bounds__(256, 4) void gemm_k(
    const unsigned short* __restrict__ A,   // GATHER ? hb : X-in (row-major 512)
    const int* __restrict__ idx,
    const unsigned short* __restrict__ Wt,
    const float* __restrict__ bias,
    unsigned short* __restrict__ Xout,
    float* __restrict__ out, const float* __restrict__ Wo,
    int mchunk0) {
  __shared__ __align__(16) char smem[35840];
  char* sA = smem;                    // 128 x 128 B = 16384
  char* sB = smem + 16384;            // 128 x 128 B = 16384
  int* sIdx = (int*)(smem + 32768);   // 128 x 4 ints = 2048
  float* sWo = (float*)(smem + 34816);  // 256 floats (FINAL only)

  const int t = threadIdx.x;
  int bx = blockIdx.x;
  // XCD swizzle: 4 col-blocks of one row-block land on one XCD.
  int xcd = bx & 7, tq = bx >> 3;
  int cbk = tq & 3;
  int rb = xcd + ((tq >> 2) << 3);
  int n0 = cbk * 128;
  int arow0 = rb * 128;               // chunk-local row base
  int w = t >> 6, l = t & 63;
  int wm = (w >> 1) * 64, wn = (w & 1) * 64;
  int m32 = l & 31, half = l >> 5;

  if (GATHER) {
    if (t < 128) {
      int m = mchunk0 + arow0 + t;
      unsigned um = (unsigned)m;
      unsigned n = um / 3u;
      int p = (int)(um - n * 3u);
      if (n >= NNODES) n = 0;  // padded tail rows: junk, guarded at output
      const unsigned pk0 = 0x320u, pk1 = 0x111u, pk2 = 0x032u, pk3 = 0x203u;
      int sh = p * 4;
      sIdx[t * 4 + 0] = idx[n * 4 + ((pk0 >> sh) & 0xFu)];
      sIdx[t * 4 + 1] = idx[n * 4 + ((pk1 >> sh) & 0xFu)];
      sIdx[t * 4 + 2] = idx[n * 4 + ((pk2 >> sh) & 0xFu)];
      sIdx[t * 4 + 3] = idx[n * 4 + ((pk3 >> sh) & 0xFu)];
    }
    __syncthreads();
  }

  f32x16 acc[2][2];
#pragma unroll
  for (int i = 0; i < 2; ++i)
#pragma unroll
    for (int j = 0; j < 2; ++j)
#pragma unroll
      for (int r = 0; r < 16; ++r) acc[i][j][r] = 0.f;

  for (int kt = 0; kt < 8; ++kt) {
    int kb = kt * 64;
    if (GATHER) {
      int jblk = kt >> 1;
      int inner = (kt & 1) * 64;
#pragma unroll
      for (int i = 0; i < 4; ++i) {
        int s = i * 256 + t;
        int r = s >> 3;
        int cl = (s & 7) ^ (r & 7);
        int src = sIdx[r * 4 + jblk];
        GLOAD_LDS16(A + (size_t)src * 128 + inner + cl * 8, sA + s * 16);
      }
    } else {
#pragma unroll
      for (int i = 0; i < 4; ++i) {
        int s = i * 256 + t;
        int r = s >> 3;
        int cl = (s & 7) ^ (r & 7);
        GLOAD_LDS16(A + (size_t)(arow0 + r) * HD + kb + cl * 8, sA + s * 16);
      }
    }
#pragma unroll
    for (int i = 0; i < 4; ++i) {
      int s = i * 256 + t;
      int r = s >> 3;
      int cl = (s & 7) ^ (r & 7);
      GLOAD_LDS16(Wt + (size_t)(n0 + r) * HD + kb + cl * 8, sB + s * 16);
    }
    __syncthreads();
    // A frag (32x32x16): m = lane&31, k = (lane>>5)*8 + j; B mirrors on n.
#pragma unroll
    for (int ks = 0; ks < 4; ++ks) {
      short8 af[2], bfr[2];
      int cb = ((ks << 1) + half) ^ (m32 & 7);  // 16B-block col, XOR-swizzled
#pragma unroll
      for (int i = 0; i < 2; ++i)
        af[i] = *(const short8*)(sA + (wm + i * 32 + m32) * 128 + cb * 16);
#pragma unroll
      for (int j = 0; j < 2; ++j)
        bfr[j] = *(const short8*)(sB + (wn + j * 32 + m32) * 128 + cb * 16);
#pragma unroll
      for (int i = 0; i < 2; ++i)
#pragma unroll
        for (int j = 0; j < 2; ++j)
          acc[i][j] = __builtin_amdgcn_mfma_f32_32x32x16_bf16(af[i], bfr[j],
                                                              acc[i][j], 0, 0, 0);
    }
    __syncthreads();
  }

  // 32x32 C/D: col = lane&31, row = (reg&3) + 8*(reg>>2) + 4*half.
  if (!FINAL) {
    // Direct acc -> global bf16 stores (2x64B segments/instr; X is L3-hot).
#pragma unroll
    for (int i = 0; i < 2; ++i)
#pragma unroll
      for (int j = 0; j < 2; ++j) {
        int coll = wn + j * 32 + m32;
        float bv = bias[n0 + coll];
        unsigned short* xp = Xout + (size_t)(arow0 + wm + i * 32) * HD + n0 + coll;
#pragma unroll
        for (int r = 0; r < 16; ++r) {
          int rowo = (r & 3) + 8 * (r >> 2) + 4 * half;
          xp[(size_t)rowo * HD] = f2bf(fmaxf(acc[i][j][r] + bv, 0.f));
        }
      }
  } else {
    if (t < 256) sWo[t] = Wo[n0 * 2 + t];  // 128 cols x 2 outputs
    unsigned short* L = (unsigned short*)smem;
    __syncthreads();  // main-loop smem reads done before overwrite
#pragma unroll
    for (int i = 0; i < 2; ++i)
#pragma unroll
      for (int j = 0; j < 2; ++j) {
        int coll = wn + j * 32 + m32;
        float bv = bias[n0 + coll];
#pragma unroll
        for (int r = 0; r < 16; ++r) {
          int rowl = wm + i * 32 + (r & 3) + 8 * (r >> 2) + 4 * half;
          float v = fmaxf(acc[i][j][r] + bv, 0.f);
          L[rowl * 136 + coll] = f2bf(v);
        }
      }
    __syncthreads();
    // 2 thr/row; volatile u32 + rotated start word -> conflict-free banks.
    int r2 = t >> 1, jo = t & 1;
    int a = (l >> 4) & 3;
    int grow = mchunk0 + arow0 + r2;
    if (grow < MTOT) {
      volatile const unsigned int* Lw =
          (volatile const unsigned int*)L + r2 * 68;
      float s = 0.f;
#pragma unroll
      for (int i = 0; i < 64; ++i) {
        int wd = (i + a) & 63;
        unsigned int pair = Lw[wd];
        s += bf2f((unsigned short)(pair & 0xffffu)) * sWo[4 * wd + jo];
        s += bf2f((unsigned short)(pair >> 16)) * sWo[4 * wd + 2 + jo];
      }
      int node = grow / 3;
      atomicAdd(out + node * 2 + jo, s);
    }
  }
}

extern "C" void kernel_launch(void* const* d_in, const int* in_sizes, int n_in,
                              void* d_out, int out_size, void* d_ws,
                              size_t ws_size, hipStream_t stream) {
  const float* h  = (const float*)d_in[0];
  const int*   ix = (const int*)d_in[1];
  const float* W1 = (const float*)d_in[2];
  const float* b1 = (const float*)d_in[3];
  const float* W2 = (const float*)d_in[4];
  const float* b2 = (const float*)d_in[5];
  const float* W3 = (const float*)d_in[6];
  const float* b3 = (const float*)d_in[7];
  const float* Wo = (const float*)d_in[8];
  const float* bo = (const float*)d_in[9];
  float* out = (float*)d_out;

  unsigned short* ws = (unsigned short*)d_ws;
  unsigned short* Wt = ws;                  // 3*512*512 shorts
  unsigned short* hb = Wt + 786432;         // 50000*128 shorts
  unsigned short* bufs = hb + 6400000;
  const size_t baseBytes = (786432ull + 6400000ull) * 2;

  // nodes per chunk: multiple of 2048 so rows%1024==0 -> RB%8==0
  size_t avail = ws_size > baseBytes ? ws_size - baseBytes : 0;
  size_t ncap = avail / (2ull * 3 * HD * sizeof(unsigned short));
  size_t nc = (ncap / 2048) * 2048;
  if (nc > 32768) nc = 32768;
  if (nc == 0) nc = 2048;  // best effort
  unsigned short* X1 = bufs;
  unsigned short* X2 = X1 + nc * 3 * HD;

  prep_w<<<3072, 256, 0, stream>>>(W1, W2, W3, Wt);
  prep_hb<<<NH * 16 / 256, 256, 0, stream>>>(h, hb);
  init_out<<<(2 * NNODES + 255) / 256, 256, 0, stream>>>(out, bo);

  for (size_t n0c = 0; n0c < NNODES; n0c += nc) {
    size_t remn = (size_t)NNODES - n0c;
    size_t ncp = remn < nc ? ((remn + 2047) / 2048) * 2048 : nc;
    int rows = (int)(ncp * 3);
    int RB = rows / 128;
    int m0 = (int)(3 * n0c);
    gemm_k<1, 0><<<RB * 4, 256, 0, stream>>>(hb, ix, Wt, b1, X1, nullptr,
                                             nullptr, m0);
    gemm_k<0, 0><<<RB * 4, 256, 0, stream>>>(X1, nullptr, Wt + 262144, b2, X2,
                                             nullptr, nullptr, m0);
    gemm_k<0, 1><<<RB * 4, 256, 0, stream>>>(X2, nullptr, Wt + 524288, b3,
                                             nullptr, out, Wo, m0);
  }
}